// Round 7
// baseline (51677.423 us; speedup 1.0000x reference)
//
#include <hip/hip_runtime.h>
#include <math.h>

// Echo-state network: sequential scan with dense 2048x2048 matvec per step.
// R7 design (post-mortem driven):
//  - R6 lesson: asm "+v" pin on a load result FORCES s_waitcnt vmcnt(0) at
//    the pin site (22.9 -> 34.6ms regression). Reverted; x is now staged
//    through LDS instead (structural fix, no scheduling games):
//      xbuf[2][128*64] (64 KB LDS): 128 steps of x per chunk, refilled once
//      per 128 steps between publish and barrier (~500cy / 128 steps).
//      Per-step xv is a ds_read_b32 -- x is OUT of the global vmcnt chain.
//  - Geometry 64 blocks x 1024 thr (32 rows/block, 2 rows/wave, 16 waves):
//    halves LLC poll readers vs R5 (the R3->R4 axis that gave -24%), and the
//    per-block h-store is now one FULL 128B line (32 contiguous floats) ->
//    kills the 4x partial-line write amplification (WRITE_SIZE 524288 KB).
//  - h broadcast: block-cooperative poll (2 words/thread, coalesced) with
//    straggler-only retry -> double-buffered LDS tile, ONE barrier/step.
//  - Sentinel sync: h stored biased +2 (ready iff >= 0.5); memset-0 and the
//    0xAA poison both read not-ready. Bias folded via tw = 2*sum(W frag).
//  - fc1/fc2 collapse: M = fc2_w@fc1_w, c2 = fc2_w@fc1_b + fc2_b - 2*rowsum(M).
//    Phase 3: GEMM states @ Mt(2048x64pad).

#define SS 16384
#define II 64
#define RR 2048
#define HH 128
#define OO 50
#define OP 64          // padded output dim
#define NBLK 64
#define NTHR 1024
#define RPB 32         // rows per block (2 per wave, 16 waves)
#define CH 128         // x-chunk steps staged in LDS
#define TT 16          // timesteps per block in out_kernel

static const size_t STATES_BYTES = (size_t)SS * RR * 4;        // 134217728
static const size_t MT_BYTES     = (size_t)RR * OP * 4;        // 524288
static const size_t C2_OFF       = STATES_BYTES + MT_BYTES;
static const size_t RS_OFF       = C2_OFF + 256;
static const size_t WS_NEED      = RS_OFF + 512 + 256;

// Opaque register pin for LOOP-INVARIANT values only (W fragments): forbids
// remat/sinking. NEVER use on in-loop load results (forces a waitcnt - R6).
#define PIN4(q) asm volatile("" : "+v"((q).x), "+v"((q).y), "+v"((q).z), "+v"((q).w))

// ---------------------------------------------------------------------------
// Persistent scan kernel. Wave w of block b owns rows R0=b*32+2w, R0+1.
// Lane l holds cols {4l+j+256m} of both rows as float4 w0q[8], w1q[8].
// ---------------------------------------------------------------------------
__global__ __launch_bounds__(NTHR, 4)
void scan_kernel(const float* __restrict__ x,
                 const float* __restrict__ Win,
                 const float* __restrict__ W,
                 float* __restrict__ states)
{
    const int tid  = threadIdx.x;
    const int blk  = blockIdx.x;
    const int wave = tid >> 6;              // 0..15
    const int lane = tid & 63;
    const int R0   = blk * RPB + wave * 2;

    // W fragments in registers/AGPRs; pinned (loop-invariant).
    float4 w0q[8], w1q[8];
#pragma unroll
    for (int m = 0; m < 8; ++m) {
        w0q[m] = *(const float4*)&W[(size_t)R0       * RR + 4 * lane + 256 * m];
        w1q[m] = *(const float4*)&W[(size_t)(R0 + 1) * RR + 4 * lane + 256 * m];
        PIN4(w0q[m]);
        PIN4(w1q[m]);
    }
    // Bias-fold constants: 2 * (sum of this lane's W fragment per row).
    float tw0 = 0.f, tw1 = 0.f;
#pragma unroll
    for (int m = 0; m < 8; ++m) {
        tw0 += w0q[m].x + w0q[m].y + w0q[m].z + w0q[m].w;
        tw1 += w1q[m].x + w1q[m].y + w1q[m].z + w1q[m].w;
    }
    tw0 *= 2.f; tw1 *= 2.f;

    // Input projection fragments (II == 64 == lanes)
    const float win0 = Win[(size_t)R0       * II + lane];
    const float win1 = Win[(size_t)(R0 + 1) * II + lane];

    __shared__ float hbuf[2][RR];           // 16 KB: biased h tiles
    __shared__ float xbuf[2][CH * II];      // 64 KB: x chunk staging

    // Prefill x chunk 0 (steps 0..127): 32 KB cooperative copy.
    {
        const float4* xg = (const float4*)x;
        float4 a = xg[tid];
        float4 b = xg[tid + NTHR];
        float4* xd = (float4*)xbuf[0];
        xd[tid]        = a;
        xd[tid + NTHR] = b;
    }
    __syncthreads();

    const int p    = lane & 1;    // even lanes finish row R0, odd R0+1
    float     hold = 0.f;

    for (int t = 0; t < SS; ++t) {
        float acc0, acc1;

        if (t > 0) {
            const float* hp = states + (size_t)(t - 1) * RR;
            float* sb = hbuf[(t - 1) & 1];
            // First pass: 2 coalesced loads/thread (block covers all 2048)
            float v0 = __hip_atomic_load(hp + tid,
                                         __ATOMIC_RELAXED, __HIP_MEMORY_SCOPE_AGENT);
            float v1 = __hip_atomic_load(hp + tid + NTHR,
                                         __ATOMIC_RELAXED, __HIP_MEMORY_SCOPE_AGENT);
            // Straggler-only batched retry (exec-masked reloads)
            for (;;) {
                if (fminf(v0, v1) >= 0.5f) break;   // ready values in (1,3)
                if (v0 < 0.5f)
                    v0 = __hip_atomic_load(hp + tid,
                                           __ATOMIC_RELAXED, __HIP_MEMORY_SCOPE_AGENT);
                if (v1 < 0.5f)
                    v1 = __hip_atomic_load(hp + tid + NTHR,
                                           __ATOMIC_RELAXED, __HIP_MEMORY_SCOPE_AGENT);
            }
            // Publish RAW biased values (stride-1024: 2-way bank alias, free)
            sb[tid]        = v0;
            sb[tid + NTHR] = v1;

            // x-chunk refill on the LAST step of each chunk: write NEXT
            // chunk into the other buffer. ~500cy vmcnt wait once / 128 steps.
            if ((t & (CH - 1)) == (CH - 1) && (t + 1) < SS) {
                const float4* xg = (const float4*)(x + (size_t)(t + 1) * II);
                float4 a = xg[tid];
                float4 b = xg[tid + NTHR];
                float4* xd = (float4*)xbuf[((t + 1) >> 7) & 1];
                xd[tid]        = a;
                xd[tid + NTHR] = b;
            }
            __syncthreads();           // the ONLY barrier per step

            // xv from LDS (ds_read_b32, off the global vmcnt chain)
            const float xv = xbuf[(t >> 7) & 1][((t & (CH - 1)) << 6) + lane];
            acc0 = win0 * xv - tw0;
            acc1 = win1 * xv - tw1;

            // Consume: 8 x ds_read_b128, each lane covers all 2048 words
            const float4* sq = (const float4*)sb;
#pragma unroll
            for (int m = 0; m < 8; ++m) {
                const float4 q = sq[lane + 64 * m];
                acc0 += w0q[m].x * q.x + w0q[m].y * q.y
                      + w0q[m].z * q.z + w0q[m].w * q.w;
                acc1 += w1q[m].x * q.x + w1q[m].y * q.y
                      + w1q[m].z * q.z + w1q[m].w * q.w;
            }
        } else {
            const float xv = xbuf[0][lane];
            acc0 = win0 * xv;
            acc1 = win1 * xv;
        }

        // Parity-combine then 5-level butterfly (6 shfls total):
        // even lanes end with full row-R0 sum, odd lanes with row-R0+1.
        {
            const float sel = p ? acc0 : acc1;     // the row NOT owned
            const float own = p ? acc1 : acc0;     // the row owned
            float a = own + __shfl_xor(sel, 1, 64);
#pragma unroll
            for (int off = 2; off <= 32; off <<= 1)
                a += __shfl_xor(a, off, 64);
            // tanh + leaky update for row R0+p
            float u = fminf(fmaxf(a, -20.f), 20.f);
            const float e  = __expf(2.f * u);
            const float th = (e - 1.f) / (e + 1.f);
            const float hn = 0.5f * hold + 0.5f * th;
            hold = hn;
            // Block stores rows blk*32..+31 contiguously = ONE 128B line.
            if (lane < 2)
                __hip_atomic_store(&states[(size_t)t * RR + R0 + lane], hn + 2.0f,
                                   __ATOMIC_RELAXED, __HIP_MEMORY_SCOPE_AGENT);
        }
    }
}

// ---------------------------------------------------------------------------
// rowsum of fc1_w rows: rs[h] = sum_r fc1_w[h][r]
// ---------------------------------------------------------------------------
__global__ void k_rowsum(const float* __restrict__ fc1w, float* __restrict__ rs)
{
    const int h = blockIdx.x;
    const int tid = threadIdx.x;
    float a = 0.f;
    for (int r = tid; r < RR; r += 256) a += fc1w[(size_t)h * RR + r];
#pragma unroll
    for (int off = 1; off <= 32; off <<= 1) a += __shfl_xor(a, off, 64);
    __shared__ float red[4];
    if ((tid & 63) == 0) red[tid >> 6] = a;
    __syncthreads();
    if (tid == 0) rs[h] = red[0] + red[1] + red[2] + red[3];
}

// ---------------------------------------------------------------------------
// Mt[r][o] = sum_h fc2_w[o][h] * fc1_w[h][r]   (o padded to 64, zeros)
// ---------------------------------------------------------------------------
__global__ void k_mt(const float* __restrict__ fc1w,
                     const float* __restrict__ fc2w,
                     float* __restrict__ Mt)
{
    __shared__ float w2[OO][HH + 1];
    const int o = threadIdx.x;         // 64
    const int r = blockIdx.x;          // 2048
    for (int i = o; i < OO * HH; i += 64) w2[i / HH][i % HH] = fc2w[i];
    __syncthreads();
    float a = 0.f;
    if (o < OO) {
        for (int h = 0; h < HH; ++h)
            a += w2[o][h] * fc1w[(size_t)h * RR + r];
    }
    Mt[r * OP + o] = a;
}

// ---------------------------------------------------------------------------
// c2[o] = fc2_b[o] + sum_h fc2_w[o][h]*(fc1_b[h] - 2*rs[h])
// ---------------------------------------------------------------------------
__global__ void k_c2(const float* __restrict__ fc2w,
                     const float* __restrict__ fc2b,
                     const float* __restrict__ fc1b,
                     const float* __restrict__ rs,
                     float* __restrict__ c2)
{
    const int o = threadIdx.x;  // 64
    float a = 0.f;
    if (o < OO) {
        for (int h = 0; h < HH; ++h)
            a += fc2w[o * HH + h] * (fc1b[h] - 2.f * rs[h]);
        a += fc2b[o];
    }
    c2[o] = a;
}

// ---------------------------------------------------------------------------
// out[t][o] = sum_r Mt[r][o] * states_biased[t][r] + c2[o]
// ---------------------------------------------------------------------------
__global__ __launch_bounds__(256)
void out_kernel(const float* __restrict__ sb,
                const float* __restrict__ Mt,
                const float* __restrict__ c2,
                float* __restrict__ out)
{
    const int tid = threadIdx.x;
    const int o   = tid & 63;
    const int tl  = tid >> 6;          // 0..3
    const int t0  = blockIdx.x * TT;
    float acc[4] = {0.f, 0.f, 0.f, 0.f};
    const float* s0 = sb + (size_t)t0 * RR;

    for (int r = 0; r < RR; r += 4) {
        float4 sv0 = *(const float4*)(s0 + (size_t)(tl + 0)  * RR + r);
        float4 sv1 = *(const float4*)(s0 + (size_t)(tl + 4)  * RR + r);
        float4 sv2 = *(const float4*)(s0 + (size_t)(tl + 8)  * RR + r);
        float4 sv3 = *(const float4*)(s0 + (size_t)(tl + 12) * RR + r);
        float m0 = Mt[(r + 0) * OP + o];
        float m1 = Mt[(r + 1) * OP + o];
        float m2 = Mt[(r + 2) * OP + o];
        float m3 = Mt[(r + 3) * OP + o];
        acc[0] += m0 * sv0.x + m1 * sv0.y + m2 * sv0.z + m3 * sv0.w;
        acc[1] += m0 * sv1.x + m1 * sv1.y + m2 * sv1.z + m3 * sv1.w;
        acc[2] += m0 * sv2.x + m1 * sv2.y + m2 * sv2.z + m3 * sv2.w;
        acc[3] += m0 * sv3.x + m1 * sv3.y + m2 * sv3.z + m3 * sv3.w;
    }
    if (o < OO) {
        const float cc = c2[o];
#pragma unroll
        for (int m = 0; m < 4; ++m) {
            const int t = t0 + tl + 4 * m;
            out[(size_t)t * OO + o] = acc[m] + cc;
        }
    }
}

extern "C" void kernel_launch(void* const* d_in, const int* in_sizes, int n_in,
                              void* d_out, int out_size, void* d_ws, size_t ws_size,
                              hipStream_t stream)
{
    const float* x    = (const float*)d_in[0];
    const float* Win  = (const float*)d_in[1];
    const float* W    = (const float*)d_in[2];
    const float* fc1w = (const float*)d_in[3];
    const float* fc1b = (const float*)d_in[4];
    const float* fc2w = (const float*)d_in[5];
    const float* fc2b = (const float*)d_in[6];
    float* out = (float*)d_out;

    if (ws_size < WS_NEED) return;

    char*  ws     = (char*)d_ws;
    float* states = (float*)ws;
    float* Mt     = (float*)(ws + STATES_BYTES);
    float* c2     = (float*)(ws + C2_OFF);
    float* rs     = (float*)(ws + RS_OFF);

    // Sentinel init: 0.0f < 0.5f means "not ready" for every h value.
    hipMemsetAsync(states, 0, STATES_BYTES, stream);

    k_rowsum<<<HH, 256, 0, stream>>>(fc1w, rs);
    k_mt<<<RR, 64, 0, stream>>>(fc1w, fc2w, Mt);
    k_c2<<<1, 64, 0, stream>>>(fc2w, fc2b, fc1b, rs, c2);

    scan_kernel<<<NBLK, NTHR, 0, stream>>>(x, Win, W, states);

    out_kernel<<<SS / TT, 256, 0, stream>>>(states, Mt, c2, out);
}